// Round 5
// baseline (444.979 us; speedup 1.0000x reference)
//
#include <hip/hip_runtime.h>
#include <math.h>

// LSTM autoencoder, MFMA, fp16 single-product numerics.
// R14 = R13 + decoder rebalance + consumer-side BN folds:
//  - z3 gate-permuted (like z2): ALL 8 waves do z3 (4 MFMA + 1 cell3/lane,
//    exact cell2 mirror). Was: waves 0-3 heavy (8 MFMA + 2 cells), 5-7 idle.
//  - BN3 folded into Wk4 rows (s3 scale in pack, t3@Wk4 into b4'), BN4 folded
//    into Wd (s4 scale, t4@Wd into bd'). Folds are fp32-exact at pack time;
//    h3/h4 were ALREADY stored raw fp16 for the recurrence, so no new state
//    quantization path (unlike R5/R7's failed fold). AH3B/AH4B deleted:
//    fewer LDS writes/reads, -2 fma -2 cvt per lane per region.
//  - z4 kk<2 now reads AH3[pd^1] == z3's A-planes: loaded ONCE into regs,
//    shared by both MFMA groups (-2 ds_read_b128/wave/region).
// Carried: spread-row map (no post-MFMA shuffles), one barrier/step,
// in-register cell2, rcpf sigmoid, weights pinned in AGPRs (enc 128 / dec
// 112-128 AGPR), 2 waves/SIMD cliff. 256 blocks x 512 threads, BT=8.

typedef _Float16 half8 __attribute__((ext_vector_type(8)));
typedef __attribute__((ext_vector_type(4))) float floatx4;

#define TT 128
#define NF 8
#define BT 8
#define NBLK 256
#define NTH 512

// packed-fragment start indices (in 512-ushort frag units, single fp16 plane)
#define FS_Z1 0     // K'=160 (Wr1 128 | Wk1 8 | pad), N=512 : 32 tiles x 5 ks
#define FS_Z2 160   // K'=192 (Wk2 128 | Wr2 64),     N=256 : 16 x 6  (cols gate-permuted)
#define FS_X3 256   // K =64  (Wk3),                  N=256 : 16 x 2  (cols gate-permuted)
#define FS_Z3 288   // K =64  (Wr3),                  N=256 : 16 x 2  (cols gate-permuted)
#define FS_Z4 320   // K'=192 (Wk4 64 *s3-folded* | Wr4 128), N=512 : 32 x 6
#define FS_DN 512   // K =128 (Wd *s4-folded*), N=16 (cols 8-15 zero) : 1 x 4
#define FS_EXT 516  // fp32 tail: b4' [512] then bd' [8]
#define N_FRAGS 516

#define MFMAH(a,b,c) __builtin_amdgcn_mfma_f32_16x16x32_f16((a),(b),(c),0,0,0)
#define PINA(v) asm volatile("" : "+a"(v))

__device__ __forceinline__ float sigmoid_(float x){
    return __builtin_amdgcn_rcpf(1.0f + __expf(-x));
}
__device__ __forceinline__ float selu_(float x){
    const float alpha = 1.6732632423543772f, scale = 1.0507009873554805f;
    return x > 0.0f ? scale*x : scale*alpha*(__expf(x)-1.0f);
}

// ---------------- pack kernel: RAW weights -> B-fragment order, fp16 --------
__global__ void pack_kernel(const float* __restrict__ Wk1, const float* __restrict__ Wr1,
                            const float* __restrict__ Wk2, const float* __restrict__ Wr2,
                            const float* __restrict__ Wk3, const float* __restrict__ Wr3,
                            const float* __restrict__ Wk4, const float* __restrict__ Wr4,
                            const float* __restrict__ Wd,
                            const float* __restrict__ g3, const float* __restrict__ v3,
                            const float* __restrict__ g4, const float* __restrict__ v4,
                            unsigned short* __restrict__ ws)
{
    const int g = blockIdx.x;
    const int l = threadIdx.x;
    int blob, fs, KS;
    if      (g < FS_Z2){ blob = 0; fs = FS_Z1; KS = 5; }
    else if (g < FS_X3){ blob = 1; fs = FS_Z2; KS = 6; }
    else if (g < FS_Z3){ blob = 2; fs = FS_X3; KS = 2; }
    else if (g < FS_Z4){ blob = 3; fs = FS_Z3; KS = 2; }
    else if (g < FS_DN){ blob = 4; fs = FS_Z4; KS = 6; }
    else               { blob = 5; fs = FS_DN; KS = 4; }
    const int fl = g - fs;
    const int tile = fl / KS, kk = fl % KS;
    const int c   = l & 15;
    const int col = tile * 16 + c;
    const int k0  = kk * 32 + (l >> 4) * 8;
    // gate-permuted column (z2/x3/z3): wave w=tile>>1 owns units 8w..8w+7
    const int oc2 = (2*(tile&1) + (c>>3))*64 + 8*(tile>>1) + (c&7);

    half8 v8;
    #pragma unroll
    for (int j = 0; j < 8; ++j){
        const int k = k0 + j;
        float v = 0.0f;
        switch (blob){
            case 0: v = (k < 128) ? Wr1[k*512 + col] : (k < 136 ? Wk1[(k-128)*512 + col] : 0.0f); break;
            case 1: v = (k < 128) ? Wk2[k*256 + oc2] : Wr2[(k-128)*256 + oc2]; break;
            case 2: v = Wk3[k*256 + oc2]; break;
            case 3: v = Wr3[k*256 + oc2]; break;
            case 4: v = (k < 64) ? Wk4[k*512 + col] * (g3[k]*rsqrtf(v3[k]+1e-3f))
                                 : Wr4[(k-64)*512 + col]; break;
            case 5: v = (col < 8) ? Wd[k*8 + col] * (g4[k]*rsqrtf(v4[k]+1e-3f)) : 0.0f; break;
        }
        v8[j] = (_Float16)v;    // RNE
    }
    *(half8*)(ws + (size_t)g*512 + l*8) = v8;
}

// ---------------- fold-bias kernel: b4' = b4 + t3@Wk4 ; bd' = bd + t4@Wd ----
__global__ void foldbias_kernel(const float* __restrict__ b4, const float* __restrict__ bd,
                                const float* __restrict__ g3, const float* __restrict__ be3,
                                const float* __restrict__ m3, const float* __restrict__ v3,
                                const float* __restrict__ g4, const float* __restrict__ be4,
                                const float* __restrict__ m4, const float* __restrict__ v4,
                                const float* __restrict__ Wk4, const float* __restrict__ Wd,
                                unsigned short* __restrict__ ws)
{
    float* wsf = (float*)(ws + (size_t)FS_EXT*512);
    const int tid = threadIdx.x;
    float s = b4[tid];
    for (int k = 0; k < 64; ++k){
        float s3 = g3[k]*rsqrtf(v3[k]+1e-3f);
        float t3 = be3[k] - m3[k]*s3;
        s += t3 * Wk4[k*512 + tid];
    }
    wsf[tid] = s;
    if (tid < 8){
        float d = bd[tid];
        for (int k = 0; k < 128; ++k){
            float s4 = g4[k]*rsqrtf(v4[k]+1e-3f);
            float t4 = be4[k] - m4[k]*s4;
            d += t4 * Wd[k*8 + tid];
        }
        wsf[512 + tid] = d;
    }
}

// ---------------- main kernel ------------------------------------------------
__global__ __launch_bounds__(NTH, 1) void lstm_ae_mfma(
    const float* __restrict__ x,
    const float* __restrict__ b1, const float* __restrict__ b2,
    const float* __restrict__ b3, const float* __restrict__ b4,
    const float* __restrict__ bd,
    const float* __restrict__ g1, const float* __restrict__ be1, const float* __restrict__ m1, const float* __restrict__ v1,
    const float* __restrict__ g2, const float* __restrict__ be2, const float* __restrict__ m2, const float* __restrict__ v2,
    const float* __restrict__ g3, const float* __restrict__ be3, const float* __restrict__ m3, const float* __restrict__ v3,
    const float* __restrict__ g4, const float* __restrict__ be4, const float* __restrict__ m4, const float* __restrict__ v4,
    const unsigned short* __restrict__ WS,
    float* __restrict__ out)
{
    // A-fragment planes, fp16: [buf][kk][lane*8+j]
    // spread-row map: batch row br lives at A-row (br&1)+4*(br>>1);
    // A-rows {2,3,6,7,10,11,14,15} stay exact zero forever.
    __shared__ __align__(16) _Float16 AZ1[2][5][512];   // h1 (kk 0-3) + x (kk 4)
    __shared__ __align__(16) _Float16 AH1B[2][4][512];  // BN1(h1), double-buffered
    __shared__ __align__(16) _Float16 AH2[2][2][512];
    __shared__ __align__(16) _Float16 AH3[2][2][512];   // raw h3 (z3 + folded z4 kk<2)
    __shared__ __align__(16) _Float16 AH4[2][4][512];   // raw h4 (z4 + folded dense)
    __shared__ __align__(16) _Float16 ENC[2][512];      // BN2(enc) scratch

    const int tid = threadIdx.x;
    const int w = tid >> 6, l = tid & 63;
    const int l15 = l & 15, q = l >> 4;
    const int h8 = (l15 >> 3) & 1;      // gate-exchange side for cell2/cell3
    const int b0 = blockIdx.x * BT;
    const int arow0 = 4*q;              // lane's A-rows 4q,4q+1 = batch 2q,2q+1

    // ---- per-lane constants ----
    const int u1 = 16*w + l15;                   // z1/z4 cell column (0..127)
    const int kk1 = u1 >> 5;
    const int sbase1 = ((u1>>3)&3)*128 + (u1&7);
    const float s1v = g1[u1]*rsqrtf(v1[u1]+1e-3f), t1v = be1[u1]-m1[u1]*s1v;

    // gate-permuted unit mapping shared by cell2 and cell3: one cell/lane
    const int un = 8*w + (l15 & 7);              // unit 0..63
    const int s2w = (w&3)*128 + (arow0 + h8)*8 + (l15&7); // A-index, plane w>>2
    const float s2v = g2[un]*rsqrtf(v2[un]+1e-3f), t2v = be2[un]-m2[un]*s2v;

    const float* wsf = (const float*)(WS + (size_t)FS_EXT*512);

    float z1b[4], z4b[4], z2b[2], z3b[2];
    #pragma unroll
    for (int i = 0; i < 4; ++i){
        z1b[i] = b1[(w + 8*i)*16 + l15];
        z4b[i] = wsf[(w + 8*i)*16 + l15];        // folded b4'
    }
    #pragma unroll
    for (int i = 0; i < 2; ++i){
        z2b[i] = b2[(2*i + h8)*64 + un];         // permuted-column bias
        z3b[i] = b3[(2*i + h8)*64 + un];
    }
    const float bdv = (w == 4 && l15 < 8) ? wsf[512 + l15] : 0.0f;  // folded bd'

    // ---- encoder weights pinned in AGPRs (128 AGPR) ----
    half8 wz1[4][5], wz2[2][6];
    #pragma unroll
    for (int i = 0; i < 4; ++i)
        #pragma unroll
        for (int kk = 0; kk < 5; ++kk){
            wz1[i][kk] = *(const half8*)(WS + (size_t)(FS_Z1 + (w+8*i)*5 + kk)*512 + l*8);
            PINA(wz1[i][kk]);
        }
    #pragma unroll
    for (int i = 0; i < 2; ++i)
        #pragma unroll
        for (int kk = 0; kk < 6; ++kk){
            wz2[i][kk] = *(const half8*)(WS + (size_t)(FS_Z2 + (2*w+i)*6 + kk)*512 + l*8);
            PINA(wz2[i][kk]);
        }

    // ---- prologue: zero all planes, stage x(0) at spread rows ----
    for (int i = tid; i < 2560; i += NTH) ((int*)AZ1)[i] = 0;
    for (int i = tid; i < 2048; i += NTH){ ((int*)AH1B)[i] = 0; ((int*)AH4)[i] = 0; }
    for (int i = tid; i < 1024; i += NTH){ ((int*)AH2)[i] = 0; ((int*)AH3)[i] = 0; }
    for (int i = tid; i < 512;  i += NTH) ((int*)ENC)[i] = 0;
    if (tid < 64){
        const int br = tid >> 3, ar = (br & 1) + 4*(br >> 1);
        AZ1[0][4][ar*8 + (tid&7)] = (_Float16)x[(size_t)(b0+br)*(TT*NF) + (tid&7)];
    }
    float c1r[2] = {0,0}, c4r[2] = {0,0};
    float c2r = 0.0f, c3r = 0.0f, h2last = 0.0f;
    __syncthreads();

    // ===================== encoder: ONE barrier per step =====================
    // region_t: z1(t+1)+cell1(t+1) | z2(t)+cell2(t)   (t = -1 .. TT-1)
    for (int t = -1; t < TT; ++t){
        const int pe = t & 1;      // (-1)&1 == 1
        if (t + 1 < TT){
            float xnext = 0.0f;
            if (tid < 64 && t + 2 < TT)
                xnext = x[(size_t)(b0+(tid>>3))*(TT*NF) + (size_t)(t+2)*NF + (tid&7)];

            // --- z1(t+1): A from AZ1[pe^1], B from AGPR ---
            floatx4 acc[4];
            #pragma unroll
            for (int i = 0; i < 4; ++i) acc[i] = (floatx4){z1b[i],z1b[i],z1b[i],z1b[i]};
            #pragma unroll
            for (int kk = 0; kk < 5; ++kk){
                half8 a = *(const half8*)&AZ1[pe^1][kk][l*8];
                #pragma unroll
                for (int i = 0; i < 4; ++i)
                    acc[i] = MFMAH(a, wz1[i][kk], acc[i]);
            }
            // --- cell1(t+1): regs 0,1 are this lane's rows -- NO shuffle ---
            #pragma unroll
            for (int r = 0; r < 2; ++r){
                float ig = sigmoid_(acc[0][r]);
                float fg = sigmoid_(acc[1][r]);
                float gg = selu_(acc[2][r]);
                float og = sigmoid_(acc[3][r]);
                float c = fg*c1r[r] + ig*gg; c1r[r] = c;
                float h = og*selu_(c);
                const int s = sbase1 + (arow0 + r)*8;
                AZ1[pe][kk1][s]    = (_Float16)h;
                AH1B[pe^1][kk1][s] = (_Float16)(h*s1v + t1v);
            }
            if (tid < 64 && t + 2 < TT){
                const int br = tid >> 3, ar = (br & 1) + 4*(br >> 1);
                AZ1[pe][4][ar*8 + (tid&7)] = (_Float16)xnext;
            }
        }
        if (t >= 0){
            // --- z2(t): A kk<4 = AH1B[pe], kk>=4 = AH2[pe] ---
            floatx4 a2[2];
            #pragma unroll
            for (int i = 0; i < 2; ++i) a2[i] = (floatx4){z2b[i],z2b[i],z2b[i],z2b[i]};
            #pragma unroll
            for (int kk = 0; kk < 6; ++kk){
                half8 a = (kk < 4) ? *(const half8*)&AH1B[pe][kk][l*8]
                                   : *(const half8*)&AH2[pe][kk-4][l*8];
                #pragma unroll
                for (int i = 0; i < 2; ++i)
                    a2[i] = MFMAH(a, wz2[i][kk], a2[i]);
            }
            // --- cell2(t) in-register: one xor-8 exchange stage ---
            float keep0 = h8 ? a2[0][1] : a2[0][0];
            float keep1 = h8 ? a2[1][1] : a2[1][0];
            float give0 = h8 ? a2[0][0] : a2[0][1];
            float give1 = h8 ? a2[1][0] : a2[1][1];
            float e0 = __shfl_xor(give0, 8);
            float e1 = __shfl_xor(give1, 8);
            float zi = h8 ? e0    : keep0;
            float zf = h8 ? keep0 : e0;
            float zg = h8 ? e1    : keep1;
            float zo = h8 ? keep1 : e1;
            float ig = sigmoid_(zi);
            float fg = sigmoid_(zf);
            float gg = selu_(zg);
            float og = sigmoid_(zo);
            float c = fg*c2r + ig*gg; c2r = c;
            h2last = og*selu_(c);
            AH2[pe^1][w>>2][s2w] = (_Float16)h2last;
        }
        __syncthreads();
    }

    // ===================== bottleneck =====================
    // encb = BN2(h2_final) from register -> ENC planes
    ENC[w>>2][s2w] = (_Float16)(h2last*s2v + t2v);
    __syncthreads();
    // xz3 = b3 + encb@Wk3 (gate-permuted), ALL waves, 2 tiles each
    floatx4 xz3r[2];
    #pragma unroll
    for (int i = 0; i < 2; ++i) xz3r[i] = (floatx4){z3b[i],z3b[i],z3b[i],z3b[i]};
    #pragma unroll
    for (int kk = 0; kk < 2; ++kk){
        half8 a = *(const half8*)&ENC[kk][l*8];
        #pragma unroll
        for (int i = 0; i < 2; ++i){
            half8 b = *(const half8*)(WS + (size_t)(FS_X3 + (2*w+i)*2 + kk)*512 + l*8);
            xz3r[i] = MFMAH(a, b, xz3r[i]);
        }
    }

    // ---- decoder weights pinned in AGPRs (encoder AGPRs now dead) ----
    // wz4 24 frags (96) + wr3 4 frags (16) all waves; +wd4 4 frags (16) on w4.
    half8 wz4[4][6], wr3[2][2], wd4[4];
    #pragma unroll
    for (int i = 0; i < 4; ++i)
        #pragma unroll
        for (int kk = 0; kk < 6; ++kk){
            wz4[i][kk] = *(const half8*)(WS + (size_t)(FS_Z4 + (w+8*i)*6 + kk)*512 + l*8);
            PINA(wz4[i][kk]);
        }
    #pragma unroll
    for (int i = 0; i < 2; ++i)
        #pragma unroll
        for (int kk = 0; kk < 2; ++kk){
            wr3[i][kk] = *(const half8*)(WS + (size_t)(FS_Z3 + (2*w+i)*2 + kk)*512 + l*8);
            PINA(wr3[i][kk]);
        }
    if (w == 4){
        #pragma unroll
        for (int kk = 0; kk < 4; ++kk){
            wd4[kk] = *(const half8*)(WS + (size_t)(FS_DN + kk)*512 + l*8);
            PINA(wd4[kk]);
        }
    }
    __syncthreads();

    // ===================== decoder: ONE barrier per step =====================
    // region_t: z3(t+1)+cell3(t+1) (ALL waves) | dense(t-1) (w4) | z4(t)+cell4(t)
    for (int t = -1; t < TT; ++t){
        const int pd = t & 1;
        // h3(t) planes: read ONCE, feed z3's recurrent part AND z4 kk<2 (BN3 folded)
        half8 a3k0 = *(const half8*)&AH3[pd^1][0][l*8];
        half8 a3k1 = *(const half8*)&AH3[pd^1][1][l*8];
        if (t + 1 < TT){
            // --- z3(t+1): 2 gate-permuted tiles, 4 MFMA ---
            floatx4 a3[2];
            a3[0] = xz3r[0]; a3[1] = xz3r[1];
            #pragma unroll
            for (int i = 0; i < 2; ++i){
                a3[i] = MFMAH(a3k0, wr3[i][0], a3[i]);
                a3[i] = MFMAH(a3k1, wr3[i][1], a3[i]);
            }
            // --- cell3(t+1): one cell/lane (unit un, row 2q+h8) ---
            float keep0 = h8 ? a3[0][1] : a3[0][0];
            float keep1 = h8 ? a3[1][1] : a3[1][0];
            float give0 = h8 ? a3[0][0] : a3[0][1];
            float give1 = h8 ? a3[1][0] : a3[1][1];
            float e0 = __shfl_xor(give0, 8);
            float e1 = __shfl_xor(give1, 8);
            float zi = h8 ? e0    : keep0;
            float zf = h8 ? keep0 : e0;
            float zg = h8 ? e1    : keep1;
            float zo = h8 ? keep1 : e1;
            float ig = sigmoid_(zi);
            float fg = sigmoid_(zf);
            float gg = selu_(zg);
            float og = sigmoid_(zo);
            float c = fg*c3r + ig*gg; c3r = c;
            float h = og*selu_(c);
            AH3[pd][w>>2][s2w] = (_Float16)h;   // raw h3 only (BN3 folded away)
        }
        if (w == 4 && t > 0){
            // --- dense(t-1): A = raw h4 planes AH4[pd], B = s4-folded Wd ---
            floatx4 ad = (floatx4){bdv,bdv,bdv,bdv};
            #pragma unroll
            for (int kk = 0; kk < 4; ++kk){
                half8 a = *(const half8*)&AH4[pd][kk][l*8];
                ad = MFMAH(a, wd4[kk], ad);
            }
            if (l15 < 8){
                #pragma unroll
                for (int r = 0; r < 2; ++r)
                    out[(size_t)(b0 + 2*q + r)*(TT*NF) + (size_t)(t-1)*NF + l15] = ad[r];
            }
        }
        if (t >= 0){
            // --- z4(t): kk<2 = cached h3 planes (folded), kk>=2 = AH4[pd] ---
            floatx4 a4[4];
            #pragma unroll
            for (int i = 0; i < 4; ++i) a4[i] = (floatx4){z4b[i],z4b[i],z4b[i],z4b[i]};
            #pragma unroll
            for (int i = 0; i < 4; ++i){
                a4[i] = MFMAH(a3k0, wz4[i][0], a4[i]);
                a4[i] = MFMAH(a3k1, wz4[i][1], a4[i]);
            }
            #pragma unroll
            for (int kk = 2; kk < 6; ++kk){
                half8 a = *(const half8*)&AH4[pd][kk-2][l*8];
                #pragma unroll
                for (int i = 0; i < 4; ++i)
                    a4[i] = MFMAH(a, wz4[i][kk], a4[i]);
            }
            #pragma unroll
            for (int r = 0; r < 2; ++r){
                float ig = sigmoid_(a4[0][r]);
                float fg = sigmoid_(a4[1][r]);
                float gg = selu_(a4[2][r]);
                float og = sigmoid_(a4[3][r]);
                float c = fg*c4r[r] + ig*gg; c4r[r] = c;
                float h = og*selu_(c);
                const int s = sbase1 + (arow0 + r)*8;
                AH4[pd^1][kk1][s] = (_Float16)h;   // raw h4 only (BN4 folded away)
            }
        }
        __syncthreads();
    }

    // epilogue: dense for t = TT-1 (wave4); h4(TT-1) is in AH4[0] (TT even)
    if (w == 4){
        floatx4 ad = (floatx4){bdv,bdv,bdv,bdv};
        #pragma unroll
        for (int kk = 0; kk < 4; ++kk){
            half8 a = *(const half8*)&AH4[0][kk][l*8];
            ad = MFMAH(a, wd4[kk], ad);
        }
        if (l15 < 8){
            #pragma unroll
            for (int r = 0; r < 2; ++r)
                out[(size_t)(b0 + 2*q + r)*(TT*NF) + (size_t)(TT-1)*NF + l15] = ad[r];
        }
    }
}

extern "C" void kernel_launch(void* const* d_in, const int* in_sizes, int n_in,
                              void* d_out, int out_size, void* d_ws, size_t ws_size,
                              hipStream_t stream) {
    const float* x   = (const float*)d_in[0];
    const float* Wk1 = (const float*)d_in[1];  const float* Wr1 = (const float*)d_in[2];
    const float* b1  = (const float*)d_in[3];
    const float* g1  = (const float*)d_in[4];  const float* be1 = (const float*)d_in[5];
    const float* m1  = (const float*)d_in[6];  const float* v1  = (const float*)d_in[7];
    const float* Wk2 = (const float*)d_in[8];  const float* Wr2 = (const float*)d_in[9];
    const float* b2  = (const float*)d_in[10];
    const float* g2  = (const float*)d_in[11]; const float* be2 = (const float*)d_in[12];
    const float* m2  = (const float*)d_in[13]; const float* v2  = (const float*)d_in[14];
    const float* Wk3 = (const float*)d_in[15]; const float* Wr3 = (const float*)d_in[16];
    const float* b3  = (const float*)d_in[17];
    const float* g3  = (const float*)d_in[18]; const float* be3 = (const float*)d_in[19];
    const float* m3  = (const float*)d_in[20]; const float* v3  = (const float*)d_in[21];
    const float* Wk4 = (const float*)d_in[22]; const float* Wr4 = (const float*)d_in[23];
    const float* b4  = (const float*)d_in[24];
    const float* g4  = (const float*)d_in[25]; const float* be4 = (const float*)d_in[26];
    const float* m4  = (const float*)d_in[27]; const float* v4  = (const float*)d_in[28];
    const float* Wd  = (const float*)d_in[29]; const float* bd  = (const float*)d_in[30];

    unsigned short* ws = (unsigned short*)d_ws;

    pack_kernel<<<dim3(N_FRAGS), dim3(64), 0, stream>>>(Wk1, Wr1, Wk2, Wr2, Wk3, Wr3,
                                                        Wk4, Wr4, Wd, g3, v3, g4, v4, ws);
    foldbias_kernel<<<dim3(1), dim3(512), 0, stream>>>(b4, bd, g3, be3, m3, v3,
                                                       g4, be4, m4, v4, Wk4, Wd, ws);
    lstm_ae_mfma<<<dim3(NBLK), dim3(NTH), 0, stream>>>(
        x, b1, b2, b3, b4, bd,
        g1, be1, m1, v1, g2, be2, m2, v2,
        g3, be3, m3, v3, g4, be4, m4, v4,
        (const unsigned short*)ws, (float*)d_out);
}

// Round 6
// 436.742 us; speedup vs baseline: 1.0189x; 1.0189x over previous
//
#include <hip/hip_runtime.h>
#include <math.h>

// LSTM autoencoder, MFMA, fp16 single-product numerics.
// R15 = R14 + encoder-side consumer folds + log2-domain gates:
//  - BN1 folded into Wk2 (s1 scale at pack, t1@Wk2 -> b2'): z2's A-operand is
//    raw h1 == the SAME AZ1 planes z1 reads -> z2 reuses z1's A-regs
//    (-4 ds_read/wave/region), cell1 loses its 2nd store + BN fma (chain
//    tail), AH1B (8KB LDS) deleted. Mirror of R14's proven BN3/BN4 fold.
//  - BN2 folded into Wk3 (s2 scale, t2@Wk3 -> b3'): ENC scratch + one
//    barrier deleted; x3 reads AH2[0] directly.
//  - log2-domain gates: all gate weights/biases pre-scaled by log2(e) at
//    pack; sigmoid = rcp(1+exp2(-z')), selu-gate linear const absorbs ln2.
//    Removes the per-gate mul inside __expf from issue + latency chain.
//    exp2 via __builtin_amdgcn_exp2f with __has_builtin fallback.
// Carried: spread-row map, one barrier/step, in-register cell2/cell3,
// rcpf sigmoid, weights pinned in AGPRs, 2 waves/SIMD cliff (watch VGPR).
// 256 blocks x 512 threads, BT=8.

typedef _Float16 half8 __attribute__((ext_vector_type(8)));
typedef __attribute__((ext_vector_type(4))) float floatx4;

#define TT 128
#define NF 8
#define BT 8
#define NBLK 256
#define NTH 512

// packed-fragment start indices (in 512-ushort frag units, single fp16 plane)
#define FS_Z1 0     // K'=160 (Wr1 128 | Wk1 8 | pad)*log2e, N=512 : 32 x 5
#define FS_Z2 160   // K'=192 (Wk2*s1 128 | Wr2 64)*log2e,  N=256 : 16 x 6 (gate-permuted)
#define FS_X3 256   // K =64  (Wk3*s2)*log2e,               N=256 : 16 x 2 (gate-permuted)
#define FS_Z3 288   // K =64  (Wr3)*log2e,                  N=256 : 16 x 2 (gate-permuted)
#define FS_Z4 320   // K'=192 (Wk4*s3 64 | Wr4 128)*log2e,  N=512 : 32 x 6
#define FS_DN 512   // K =128 (Wd*s4), N=16 (cols 8-15 zero) : 1 x 4
#define FS_EXT 516  // fp32 tail: b4'[512] bd'[8] b2'[256] b3'[256]
#define N_FRAGS 516

#define LOG2E 1.4426950408889634f

#define MFMAH(a,b,c) __builtin_amdgcn_mfma_f32_16x16x32_f16((a),(b),(c),0,0,0)
#define PINA(v) asm volatile("" : "+a"(v))

__device__ __forceinline__ float exp2_(float x){
#if __has_builtin(__builtin_amdgcn_exp2f)
    return __builtin_amdgcn_exp2f(x);
#else
    return __expf(x * 0.6931471805599453f);
#endif
}
// gates arrive in log2 domain (z' = z*log2e)
__device__ __forceinline__ float sigmoid2_(float x){
    return __builtin_amdgcn_rcpf(1.0f + exp2_(-x));
}
__device__ __forceinline__ float selug2_(float x){
    // selu(z) with z' = z*log2e input: pos 1.0507*ln2*z', neg 1.7581*(2^z'-1)
    return x > 0.0f ? 0.7282904281f*x : 1.7580993408473766f*(exp2_(x)-1.0f);
}
__device__ __forceinline__ float selu_(float x){   // normal domain (cell state)
    const float alpha = 1.6732632423543772f, scale = 1.0507009873554805f;
    return x > 0.0f ? scale*x : scale*alpha*(__expf(x)-1.0f);
}

// ---------------- pack kernel: RAW weights -> B-fragment order, fp16 --------
__global__ void pack_kernel(const float* __restrict__ Wk1, const float* __restrict__ Wr1,
                            const float* __restrict__ Wk2, const float* __restrict__ Wr2,
                            const float* __restrict__ Wk3, const float* __restrict__ Wr3,
                            const float* __restrict__ Wk4, const float* __restrict__ Wr4,
                            const float* __restrict__ Wd,
                            const float* __restrict__ g1, const float* __restrict__ v1,
                            const float* __restrict__ g2, const float* __restrict__ v2,
                            const float* __restrict__ g3, const float* __restrict__ v3,
                            const float* __restrict__ g4, const float* __restrict__ v4,
                            unsigned short* __restrict__ ws)
{
    const int g = blockIdx.x;
    const int l = threadIdx.x;
    int blob, fs, KS;
    if      (g < FS_Z2){ blob = 0; fs = FS_Z1; KS = 5; }
    else if (g < FS_X3){ blob = 1; fs = FS_Z2; KS = 6; }
    else if (g < FS_Z3){ blob = 2; fs = FS_X3; KS = 2; }
    else if (g < FS_Z4){ blob = 3; fs = FS_Z3; KS = 2; }
    else if (g < FS_DN){ blob = 4; fs = FS_Z4; KS = 6; }
    else               { blob = 5; fs = FS_DN; KS = 4; }
    const int fl = g - fs;
    const int tile = fl / KS, kk = fl % KS;
    const int c   = l & 15;
    const int col = tile * 16 + c;
    const int k0  = kk * 32 + (l >> 4) * 8;
    // gate-permuted column (z2/x3/z3): wave w=tile>>1 owns units 8w..8w+7
    const int oc2 = (2*(tile&1) + (c>>3))*64 + 8*(tile>>1) + (c&7);

    half8 v8;
    #pragma unroll
    for (int j = 0; j < 8; ++j){
        const int k = k0 + j;
        float v = 0.0f;
        switch (blob){
            case 0: v = ((k < 128) ? Wr1[k*512 + col] : (k < 136 ? Wk1[(k-128)*512 + col] : 0.0f)) * LOG2E; break;
            case 1: v = ((k < 128) ? Wk2[k*256 + oc2] * (g1[k]*rsqrtf(v1[k]+1e-3f))
                                   : Wr2[(k-128)*256 + oc2]) * LOG2E; break;
            case 2: v = Wk3[k*256 + oc2] * (g2[k]*rsqrtf(v2[k]+1e-3f)) * LOG2E; break;
            case 3: v = Wr3[k*256 + oc2] * LOG2E; break;
            case 4: v = ((k < 64) ? Wk4[k*512 + col] * (g3[k]*rsqrtf(v3[k]+1e-3f))
                                  : Wr4[(k-64)*512 + col]) * LOG2E; break;
            case 5: v = (col < 8) ? Wd[k*8 + col] * (g4[k]*rsqrtf(v4[k]+1e-3f)) : 0.0f; break;
        }
        v8[j] = (_Float16)v;    // RNE
    }
    *(half8*)(ws + (size_t)g*512 + l*8) = v8;
}

// ---------------- fold-bias kernel ------------------------------------------
// b4' = (b4 + t3@Wk4)*log2e ; bd' = bd + t4@Wd ;
// b2' = (b2 + t1@Wk2)*log2e ; b3' = (b3 + t2@Wk3)*log2e
__global__ void foldbias_kernel(const float* __restrict__ b2, const float* __restrict__ b3,
                                const float* __restrict__ b4, const float* __restrict__ bd,
                                const float* __restrict__ g1, const float* __restrict__ be1,
                                const float* __restrict__ m1, const float* __restrict__ v1,
                                const float* __restrict__ g2, const float* __restrict__ be2,
                                const float* __restrict__ m2, const float* __restrict__ v2,
                                const float* __restrict__ g3, const float* __restrict__ be3,
                                const float* __restrict__ m3, const float* __restrict__ v3,
                                const float* __restrict__ g4, const float* __restrict__ be4,
                                const float* __restrict__ m4, const float* __restrict__ v4,
                                const float* __restrict__ Wk2, const float* __restrict__ Wk3,
                                const float* __restrict__ Wk4, const float* __restrict__ Wd,
                                unsigned short* __restrict__ ws)
{
    float* wsf = (float*)(ws + (size_t)FS_EXT*512);
    const int tid = threadIdx.x;
    {   // b4'
        float s = b4[tid];
        for (int k = 0; k < 64; ++k){
            float s3 = g3[k]*rsqrtf(v3[k]+1e-3f);
            s += (be3[k] - m3[k]*s3) * Wk4[k*512 + tid];
        }
        wsf[tid] = s * LOG2E;
    }
    if (tid < 8){
        float d = bd[tid];
        for (int k = 0; k < 128; ++k){
            float s4 = g4[k]*rsqrtf(v4[k]+1e-3f);
            d += (be4[k] - m4[k]*s4) * Wd[k*8 + tid];
        }
        wsf[512 + tid] = d;
    }
    if (tid < 256){
        float s = b2[tid];
        for (int k = 0; k < 128; ++k){
            float s1 = g1[k]*rsqrtf(v1[k]+1e-3f);
            s += (be1[k] - m1[k]*s1) * Wk2[k*256 + tid];
        }
        wsf[520 + tid] = s * LOG2E;
        float u = b3[tid];
        for (int k = 0; k < 64; ++k){
            float s2 = g2[k]*rsqrtf(v2[k]+1e-3f);
            u += (be2[k] - m2[k]*s2) * Wk3[k*256 + tid];
        }
        wsf[776 + tid] = u * LOG2E;
    }
}

// ---------------- main kernel ------------------------------------------------
__global__ __launch_bounds__(NTH, 1) void lstm_ae_mfma(
    const float* __restrict__ x,
    const float* __restrict__ b1,
    const unsigned short* __restrict__ WS,
    float* __restrict__ out)
{
    // A-fragment planes, fp16: [buf][kk][lane*8+j]; spread-row map:
    // batch row br -> A-row (br&1)+4*(br>>1); other A-rows stay exact zero.
    __shared__ __align__(16) _Float16 AZ1[2][5][512];   // raw h1 (kk 0-3) + x (kk 4)
    __shared__ __align__(16) _Float16 AH2[2][2][512];   // raw h2
    __shared__ __align__(16) _Float16 AH3[2][2][512];   // raw h3
    __shared__ __align__(16) _Float16 AH4[2][4][512];   // raw h4

    const int tid = threadIdx.x;
    const int w = tid >> 6, l = tid & 63;
    const int l15 = l & 15, q = l >> 4;
    const int h8 = (l15 >> 3) & 1;      // gate-exchange side for cell2/cell3
    const int b0 = blockIdx.x * BT;
    const int arow0 = 4*q;              // lane's A-rows 4q,4q+1 = batch 2q,2q+1

    // ---- per-lane constants ----
    const int u1 = 16*w + l15;                   // z1/z4 cell column (0..127)
    const int kk1 = u1 >> 5;
    const int sbase1 = ((u1>>3)&3)*128 + (u1&7);

    // gate-permuted unit mapping shared by cell2 and cell3: one cell/lane
    const int un = 8*w + (l15 & 7);              // unit 0..63
    const int s2w = (w&3)*128 + (arow0 + h8)*8 + (l15&7); // A-index, plane w>>2

    const float* wsf = (const float*)(WS + (size_t)FS_EXT*512);

    float z1b[4], z4b[4], z2b[2], z3b[2];
    #pragma unroll
    for (int i = 0; i < 4; ++i){
        z1b[i] = b1[(w + 8*i)*16 + l15] * LOG2E;
        z4b[i] = wsf[(w + 8*i)*16 + l15];        // folded b4' (log2 domain)
    }
    #pragma unroll
    for (int i = 0; i < 2; ++i){
        z2b[i] = wsf[520 + (2*i + h8)*64 + un];  // folded b2'
        z3b[i] = wsf[776 + (2*i + h8)*64 + un];  // folded b3'
    }
    const float bdv = (w == 4 && l15 < 8) ? wsf[512 + l15] : 0.0f;  // folded bd'

    // ---- encoder weights pinned in AGPRs (128 AGPR) ----
    half8 wz1[4][5], wz2[2][6];
    #pragma unroll
    for (int i = 0; i < 4; ++i)
        #pragma unroll
        for (int kk = 0; kk < 5; ++kk){
            wz1[i][kk] = *(const half8*)(WS + (size_t)(FS_Z1 + (w+8*i)*5 + kk)*512 + l*8);
            PINA(wz1[i][kk]);
        }
    #pragma unroll
    for (int i = 0; i < 2; ++i)
        #pragma unroll
        for (int kk = 0; kk < 6; ++kk){
            wz2[i][kk] = *(const half8*)(WS + (size_t)(FS_Z2 + (2*w+i)*6 + kk)*512 + l*8);
            PINA(wz2[i][kk]);
        }

    // ---- prologue: zero all planes, stage x(0) at spread rows ----
    for (int i = tid; i < 2560; i += NTH) ((int*)AZ1)[i] = 0;
    for (int i = tid; i < 2048; i += NTH) ((int*)AH4)[i] = 0;
    for (int i = tid; i < 1024; i += NTH){ ((int*)AH2)[i] = 0; ((int*)AH3)[i] = 0; }
    if (tid < 64){
        const int br = tid >> 3, ar = (br & 1) + 4*(br >> 1);
        AZ1[0][4][ar*8 + (tid&7)] = (_Float16)x[(size_t)(b0+br)*(TT*NF) + (tid&7)];
    }
    float c1r[2] = {0,0}, c4r[2] = {0,0};
    float c2r = 0.0f, c3r = 0.0f;
    __syncthreads();

    // ===================== encoder: ONE barrier per step =====================
    // region_t: z1(t+1)+cell1(t+1) | z2(t)+cell2(t)   (t = -1 .. TT-1)
    // z2 kk<4 reuses z1's A-planes (raw h1; BN1 folded into Wk2).
    for (int t = -1; t < TT; ++t){
        const int pe = t & 1;      // (-1)&1 == 1
        half8 a5[5];
        #pragma unroll
        for (int kk = 0; kk < 5; ++kk)
            a5[kk] = *(const half8*)&AZ1[pe^1][kk][l*8];
        if (t + 1 < TT){
            float xnext = 0.0f;
            if (tid < 64 && t + 2 < TT)
                xnext = x[(size_t)(b0+(tid>>3))*(TT*NF) + (size_t)(t+2)*NF + (tid&7)];

            // --- z1(t+1): A = a5 planes, B from AGPR ---
            floatx4 acc[4];
            #pragma unroll
            for (int i = 0; i < 4; ++i) acc[i] = (floatx4){z1b[i],z1b[i],z1b[i],z1b[i]};
            #pragma unroll
            for (int kk = 0; kk < 5; ++kk)
                #pragma unroll
                for (int i = 0; i < 4; ++i)
                    acc[i] = MFMAH(a5[kk], wz1[i][kk], acc[i]);
            // --- cell1(t+1): regs 0,1 are this lane's rows; raw h only ---
            #pragma unroll
            for (int r = 0; r < 2; ++r){
                float ig = sigmoid2_(acc[0][r]);
                float fg = sigmoid2_(acc[1][r]);
                float gg = selug2_(acc[2][r]);
                float og = sigmoid2_(acc[3][r]);
                float c = fg*c1r[r] + ig*gg; c1r[r] = c;
                float h = og*selu_(c);
                AZ1[pe][kk1][sbase1 + (arow0 + r)*8] = (_Float16)h;
            }
            if (tid < 64 && t + 2 < TT){
                const int br = tid >> 3, ar = (br & 1) + 4*(br >> 1);
                AZ1[pe][4][ar*8 + (tid&7)] = (_Float16)xnext;
            }
        }
        if (t >= 0){
            // --- z2(t): A kk<4 = a5[kk] (raw h1, fold), kk>=4 = AH2[pe] ---
            floatx4 a2[2];
            #pragma unroll
            for (int i = 0; i < 2; ++i) a2[i] = (floatx4){z2b[i],z2b[i],z2b[i],z2b[i]};
            #pragma unroll
            for (int kk = 0; kk < 4; ++kk)
                #pragma unroll
                for (int i = 0; i < 2; ++i)
                    a2[i] = MFMAH(a5[kk], wz2[i][kk], a2[i]);
            #pragma unroll
            for (int kk = 4; kk < 6; ++kk){
                half8 a = *(const half8*)&AH2[pe][kk-4][l*8];
                #pragma unroll
                for (int i = 0; i < 2; ++i)
                    a2[i] = MFMAH(a, wz2[i][kk], a2[i]);
            }
            // --- cell2(t) in-register: one xor-8 exchange stage ---
            float keep0 = h8 ? a2[0][1] : a2[0][0];
            float keep1 = h8 ? a2[1][1] : a2[1][0];
            float give0 = h8 ? a2[0][0] : a2[0][1];
            float give1 = h8 ? a2[1][0] : a2[1][1];
            float e0 = __shfl_xor(give0, 8);
            float e1 = __shfl_xor(give1, 8);
            float zi = h8 ? e0    : keep0;
            float zf = h8 ? keep0 : e0;
            float zg = h8 ? e1    : keep1;
            float zo = h8 ? keep1 : e1;
            float ig = sigmoid2_(zi);
            float fg = sigmoid2_(zf);
            float gg = selug2_(zg);
            float og = sigmoid2_(zo);
            float c = fg*c2r + ig*gg; c2r = c;
            float h2 = og*selu_(c);
            AH2[pe^1][w>>2][s2w] = (_Float16)h2;
        }
        __syncthreads();
    }

    // ===================== bottleneck =====================
    // h2(TT-1) planes are in AH2[0] (raw; BN2 folded into Wk3).
    // xz3 = b3' + h2@(s2*Wk3) (gate-permuted), ALL waves, 2 tiles each.
    floatx4 xz3r[2];
    #pragma unroll
    for (int i = 0; i < 2; ++i) xz3r[i] = (floatx4){z3b[i],z3b[i],z3b[i],z3b[i]};
    #pragma unroll
    for (int kk = 0; kk < 2; ++kk){
        half8 a = *(const half8*)&AH2[0][kk][l*8];
        #pragma unroll
        for (int i = 0; i < 2; ++i){
            half8 b = *(const half8*)(WS + (size_t)(FS_X3 + (2*w+i)*2 + kk)*512 + l*8);
            xz3r[i] = MFMAH(a, b, xz3r[i]);
        }
    }

    // ---- decoder weights pinned in AGPRs (encoder AGPRs now dead) ----
    half8 wz4[4][6], wr3[2][2], wd4[4];
    #pragma unroll
    for (int i = 0; i < 4; ++i)
        #pragma unroll
        for (int kk = 0; kk < 6; ++kk){
            wz4[i][kk] = *(const half8*)(WS + (size_t)(FS_Z4 + (w+8*i)*6 + kk)*512 + l*8);
            PINA(wz4[i][kk]);
        }
    #pragma unroll
    for (int i = 0; i < 2; ++i)
        #pragma unroll
        for (int kk = 0; kk < 2; ++kk){
            wr3[i][kk] = *(const half8*)(WS + (size_t)(FS_Z3 + (2*w+i)*2 + kk)*512 + l*8);
            PINA(wr3[i][kk]);
        }
    if (w == 4){
        #pragma unroll
        for (int kk = 0; kk < 4; ++kk){
            wd4[kk] = *(const half8*)(WS + (size_t)(FS_DN + kk)*512 + l*8);
            PINA(wd4[kk]);
        }
    }
    __syncthreads();

    // ===================== decoder: ONE barrier per step =====================
    // region_t: z3(t+1)+cell3(t+1) (ALL waves) | dense(t-1) (w4) | z4(t)+cell4(t)
    for (int t = -1; t < TT; ++t){
        const int pd = t & 1;
        // h3(t) planes: read ONCE, feed z3's recurrent part AND z4 kk<2 (fold)
        half8 a3k0 = *(const half8*)&AH3[pd^1][0][l*8];
        half8 a3k1 = *(const half8*)&AH3[pd^1][1][l*8];
        if (t + 1 < TT){
            // --- z3(t+1): 2 gate-permuted tiles, 4 MFMA ---
            floatx4 a3[2];
            a3[0] = xz3r[0]; a3[1] = xz3r[1];
            #pragma unroll
            for (int i = 0; i < 2; ++i){
                a3[i] = MFMAH(a3k0, wr3[i][0], a3[i]);
                a3[i] = MFMAH(a3k1, wr3[i][1], a3[i]);
            }
            // --- cell3(t+1): one cell/lane (unit un, row 2q+h8) ---
            float keep0 = h8 ? a3[0][1] : a3[0][0];
            float keep1 = h8 ? a3[1][1] : a3[1][0];
            float give0 = h8 ? a3[0][0] : a3[0][1];
            float give1 = h8 ? a3[1][0] : a3[1][1];
            float e0 = __shfl_xor(give0, 8);
            float e1 = __shfl_xor(give1, 8);
            float zi = h8 ? e0    : keep0;
            float zf = h8 ? keep0 : e0;
            float zg = h8 ? e1    : keep1;
            float zo = h8 ? keep1 : e1;
            float ig = sigmoid2_(zi);
            float fg = sigmoid2_(zf);
            float gg = selug2_(zg);
            float og = sigmoid2_(zo);
            float c = fg*c3r + ig*gg; c3r = c;
            float h = og*selu_(c);
            AH3[pd][w>>2][s2w] = (_Float16)h;   // raw h3 (BN3 folded away)
        }
        if (w == 4 && t > 0){
            // --- dense(t-1): A = raw h4 planes AH4[pd], B = s4-folded Wd ---
            floatx4 ad = (floatx4){bdv,bdv,bdv,bdv};
            #pragma unroll
            for (int kk = 0; kk < 4; ++kk){
                half8 a = *(const half8*)&AH4[pd][kk][l*8];
                ad = MFMAH(a, wd4[kk], ad);
            }
            if (l15 < 8){
                #pragma unroll
                for (int r = 0; r < 2; ++r)
                    out[(size_t)(b0 + 2*q + r)*(TT*NF) + (size_t)(t-1)*NF + l15] = ad[r];
            }
        }
        if (t >= 0){
            // --- z4(t): kk<2 = cached h3 planes (folded), kk>=2 = AH4[pd] ---
            floatx4 a4[4];
            #pragma unroll
            for (int i = 0; i < 4; ++i) a4[i] = (floatx4){z4b[i],z4b[i],z4b[i],z4b[i]};
            #pragma unroll
            for (int i = 0; i < 4; ++i){
                a4[i] = MFMAH(a3k0, wz4[i][0], a4[i]);
                a4[i] = MFMAH(a3k1, wz4[i][1], a4[i]);
            }
            #pragma unroll
            for (int kk = 2; kk < 6; ++kk){
                half8 a = *(const half8*)&AH4[pd][kk-2][l*8];
                #pragma unroll
                for (int i = 0; i < 4; ++i)
                    a4[i] = MFMAH(a, wz4[i][kk], a4[i]);
            }
            #pragma unroll
            for (int r = 0; r < 2; ++r){
                float ig = sigmoid2_(a4[0][r]);
                float fg = sigmoid2_(a4[1][r]);
                float gg = selug2_(a4[2][r]);
                float og = sigmoid2_(a4[3][r]);
                float c = fg*c4r[r] + ig*gg; c4r[r] = c;
                float h = og*selu_(c);
                AH4[pd^1][kk1][sbase1 + (arow0 + r)*8] = (_Float16)h;  // raw h4
            }
        }
        __syncthreads();
    }

    // epilogue: dense for t = TT-1 (wave4); h4(TT-1) is in AH4[0] (TT even)
    if (w == 4){
        floatx4 ad = (floatx4){bdv,bdv,bdv,bdv};
        #pragma unroll
        for (int kk = 0; kk < 4; ++kk){
            half8 a = *(const half8*)&AH4[0][kk][l*8];
            ad = MFMAH(a, wd4[kk], ad);
        }
        if (l15 < 8){
            #pragma unroll
            for (int r = 0; r < 2; ++r)
                out[(size_t)(b0 + 2*q + r)*(TT*NF) + (size_t)(TT-1)*NF + l15] = ad[r];
        }
    }
}

extern "C" void kernel_launch(void* const* d_in, const int* in_sizes, int n_in,
                              void* d_out, int out_size, void* d_ws, size_t ws_size,
                              hipStream_t stream) {
    const float* x   = (const float*)d_in[0];
    const float* Wk1 = (const float*)d_in[1];  const float* Wr1 = (const float*)d_in[2];
    const float* b1  = (const float*)d_in[3];
    const float* g1  = (const float*)d_in[4];  const float* be1 = (const float*)d_in[5];
    const float* m1  = (const float*)d_in[6];  const float* v1  = (const float*)d_in[7];
    const float* Wk2 = (const float*)d_in[8];  const float* Wr2 = (const float*)d_in[9];
    const float* b2  = (const float*)d_in[10];
    const float* g2  = (const float*)d_in[11]; const float* be2 = (const float*)d_in[12];
    const float* m2  = (const float*)d_in[13]; const float* v2  = (const float*)d_in[14];
    const float* Wk3 = (const float*)d_in[15]; const float* Wr3 = (const float*)d_in[16];
    const float* b3  = (const float*)d_in[17];
    const float* g3  = (const float*)d_in[18]; const float* be3 = (const float*)d_in[19];
    const float* m3  = (const float*)d_in[20]; const float* v3  = (const float*)d_in[21];
    const float* Wk4 = (const float*)d_in[22]; const float* Wr4 = (const float*)d_in[23];
    const float* b4  = (const float*)d_in[24];
    const float* g4  = (const float*)d_in[25]; const float* be4 = (const float*)d_in[26];
    const float* m4  = (const float*)d_in[27]; const float* v4  = (const float*)d_in[28];
    const float* Wd  = (const float*)d_in[29]; const float* bd  = (const float*)d_in[30];

    unsigned short* ws = (unsigned short*)d_ws;

    pack_kernel<<<dim3(N_FRAGS), dim3(64), 0, stream>>>(Wk1, Wr1, Wk2, Wr2, Wk3, Wr3,
                                                        Wk4, Wr4, Wd,
                                                        g1, v1, g2, v2, g3, v3, g4, v4, ws);
    foldbias_kernel<<<dim3(1), dim3(512), 0, stream>>>(b2, b3, b4, bd,
                                                       g1, be1, m1, v1, g2, be2, m2, v2,
                                                       g3, be3, m3, v3, g4, be4, m4, v4,
                                                       Wk2, Wk3, Wk4, Wd, ws);
    lstm_ae_mfma<<<dim3(NBLK), dim3(NTH), 0, stream>>>(
        x, b1, (const unsigned short*)ws, (float*)d_out);
}

// Round 7
// 431.906 us; speedup vs baseline: 1.0303x; 1.0112x over previous
//
#include <hip/hip_runtime.h>
#include <math.h>

// LSTM autoencoder, MFMA, fp16 single-product numerics.
// R16 = R15 + instruction-count consolidation (issue-bound: VALU 56% + MFMA
// 34.5% ~= 91% combined on the single issue port at the 2-wave/SIMD cliff):
//  - literal-phase unroll-2: t-loop peeled (t=-1) + unrolled in (PE=0,PE=1)
//    pairs via macros with LITERAL PE -> all double-buffer LDS addresses
//    constant-fold into ds offset: immediates (kills per-region addr VALU).
//  - dense-wave alternation: dense(t-1) on w4 for odd t, w5 for even t
//    (was: w4 every region = barrier straggler). Both pin Wd (AGPR still 128).
//  - __launch_bounds__(512,2) pins the allocator to the 256-reg budget.
// Carried from R15: consumer-side BN folds (BN1->Wk2, BN2->Wk3, BN3->Wk4,
// BN4->Wd; fp32-exact at pack), log2-domain gates, spread-row map, one
// barrier/step, in-register cell2/cell3, rcpf sigmoid, weights in AGPRs.
// 256 blocks x 512 threads, BT=8.

typedef _Float16 half8 __attribute__((ext_vector_type(8)));
typedef __attribute__((ext_vector_type(4))) float floatx4;

#define TT 128
#define NF 8
#define BT 8
#define NBLK 256
#define NTH 512

// packed-fragment start indices (in 512-ushort frag units, single fp16 plane)
#define FS_Z1 0     // K'=160 (Wr1 128 | Wk1 8 | pad)*log2e, N=512 : 32 x 5
#define FS_Z2 160   // K'=192 (Wk2*s1 128 | Wr2 64)*log2e,  N=256 : 16 x 6 (gate-permuted)
#define FS_X3 256   // K =64  (Wk3*s2)*log2e,               N=256 : 16 x 2 (gate-permuted)
#define FS_Z3 288   // K =64  (Wr3)*log2e,                  N=256 : 16 x 2 (gate-permuted)
#define FS_Z4 320   // K'=192 (Wk4*s3 64 | Wr4 128)*log2e,  N=512 : 32 x 6
#define FS_DN 512   // K =128 (Wd*s4), N=16 (cols 8-15 zero) : 1 x 4
#define FS_EXT 516  // fp32 tail: b4'[512] bd'[8] b2'[256] b3'[256]
#define N_FRAGS 516

#define LOG2E 1.4426950408889634f

#define MFMAH(a,b,c) __builtin_amdgcn_mfma_f32_16x16x32_f16((a),(b),(c),0,0,0)
#define PINA(v) asm volatile("" : "+a"(v))

__device__ __forceinline__ float exp2_(float x){
#if __has_builtin(__builtin_amdgcn_exp2f)
    return __builtin_amdgcn_exp2f(x);
#else
    return __expf(x * 0.6931471805599453f);
#endif
}
// gates arrive in log2 domain (z' = z*log2e)
__device__ __forceinline__ float sigmoid2_(float x){
    return __builtin_amdgcn_rcpf(1.0f + exp2_(-x));
}
__device__ __forceinline__ float selug2_(float x){
    // selu(z) with z' = z*log2e input: pos 1.0507*ln2*z', neg 1.7581*(2^z'-1)
    return x > 0.0f ? 0.7282904281f*x : 1.7580993408473766f*(exp2_(x)-1.0f);
}
__device__ __forceinline__ float selu_(float x){   // normal domain (cell state)
    const float alpha = 1.6732632423543772f, scale = 1.0507009873554805f;
    return x > 0.0f ? scale*x : scale*alpha*(__expf(x)-1.0f);
}

// ---------------- pack kernel: RAW weights -> B-fragment order, fp16 --------
__global__ void pack_kernel(const float* __restrict__ Wk1, const float* __restrict__ Wr1,
                            const float* __restrict__ Wk2, const float* __restrict__ Wr2,
                            const float* __restrict__ Wk3, const float* __restrict__ Wr3,
                            const float* __restrict__ Wk4, const float* __restrict__ Wr4,
                            const float* __restrict__ Wd,
                            const float* __restrict__ g1, const float* __restrict__ v1,
                            const float* __restrict__ g2, const float* __restrict__ v2,
                            const float* __restrict__ g3, const float* __restrict__ v3,
                            const float* __restrict__ g4, const float* __restrict__ v4,
                            unsigned short* __restrict__ ws)
{
    const int g = blockIdx.x;
    const int l = threadIdx.x;
    int blob, fs, KS;
    if      (g < FS_Z2){ blob = 0; fs = FS_Z1; KS = 5; }
    else if (g < FS_X3){ blob = 1; fs = FS_Z2; KS = 6; }
    else if (g < FS_Z3){ blob = 2; fs = FS_X3; KS = 2; }
    else if (g < FS_Z4){ blob = 3; fs = FS_Z3; KS = 2; }
    else if (g < FS_DN){ blob = 4; fs = FS_Z4; KS = 6; }
    else               { blob = 5; fs = FS_DN; KS = 4; }
    const int fl = g - fs;
    const int tile = fl / KS, kk = fl % KS;
    const int c   = l & 15;
    const int col = tile * 16 + c;
    const int k0  = kk * 32 + (l >> 4) * 8;
    // gate-permuted column (z2/x3/z3): wave w=tile>>1 owns units 8w..8w+7
    const int oc2 = (2*(tile&1) + (c>>3))*64 + 8*(tile>>1) + (c&7);

    half8 v8;
    #pragma unroll
    for (int j = 0; j < 8; ++j){
        const int k = k0 + j;
        float v = 0.0f;
        switch (blob){
            case 0: v = ((k < 128) ? Wr1[k*512 + col] : (k < 136 ? Wk1[(k-128)*512 + col] : 0.0f)) * LOG2E; break;
            case 1: v = ((k < 128) ? Wk2[k*256 + oc2] * (g1[k]*rsqrtf(v1[k]+1e-3f))
                                   : Wr2[(k-128)*256 + oc2]) * LOG2E; break;
            case 2: v = Wk3[k*256 + oc2] * (g2[k]*rsqrtf(v2[k]+1e-3f)) * LOG2E; break;
            case 3: v = Wr3[k*256 + oc2] * LOG2E; break;
            case 4: v = ((k < 64) ? Wk4[k*512 + col] * (g3[k]*rsqrtf(v3[k]+1e-3f))
                                  : Wr4[(k-64)*512 + col]) * LOG2E; break;
            case 5: v = (col < 8) ? Wd[k*8 + col] * (g4[k]*rsqrtf(v4[k]+1e-3f)) : 0.0f; break;
        }
        v8[j] = (_Float16)v;    // RNE
    }
    *(half8*)(ws + (size_t)g*512 + l*8) = v8;
}

// ---------------- fold-bias kernel ------------------------------------------
// b4' = (b4 + t3@Wk4)*log2e ; bd' = bd + t4@Wd ;
// b2' = (b2 + t1@Wk2)*log2e ; b3' = (b3 + t2@Wk3)*log2e
__global__ void foldbias_kernel(const float* __restrict__ b2, const float* __restrict__ b3,
                                const float* __restrict__ b4, const float* __restrict__ bd,
                                const float* __restrict__ g1, const float* __restrict__ be1,
                                const float* __restrict__ m1, const float* __restrict__ v1,
                                const float* __restrict__ g2, const float* __restrict__ be2,
                                const float* __restrict__ m2, const float* __restrict__ v2,
                                const float* __restrict__ g3, const float* __restrict__ be3,
                                const float* __restrict__ m3, const float* __restrict__ v3,
                                const float* __restrict__ g4, const float* __restrict__ be4,
                                const float* __restrict__ m4, const float* __restrict__ v4,
                                const float* __restrict__ Wk2, const float* __restrict__ Wk3,
                                const float* __restrict__ Wk4, const float* __restrict__ Wd,
                                unsigned short* __restrict__ ws)
{
    float* wsf = (float*)(ws + (size_t)FS_EXT*512);
    const int tid = threadIdx.x;
    {   // b4'
        float s = b4[tid];
        for (int k = 0; k < 64; ++k){
            float s3 = g3[k]*rsqrtf(v3[k]+1e-3f);
            s += (be3[k] - m3[k]*s3) * Wk4[k*512 + tid];
        }
        wsf[tid] = s * LOG2E;
    }
    if (tid < 8){
        float d = bd[tid];
        for (int k = 0; k < 128; ++k){
            float s4 = g4[k]*rsqrtf(v4[k]+1e-3f);
            d += (be4[k] - m4[k]*s4) * Wd[k*8 + tid];
        }
        wsf[512 + tid] = d;
    }
    if (tid < 256){
        float s = b2[tid];
        for (int k = 0; k < 128; ++k){
            float s1 = g1[k]*rsqrtf(v1[k]+1e-3f);
            s += (be1[k] - m1[k]*s1) * Wk2[k*256 + tid];
        }
        wsf[520 + tid] = s * LOG2E;
        float u = b3[tid];
        for (int k = 0; k < 64; ++k){
            float s2 = g2[k]*rsqrtf(v2[k]+1e-3f);
            u += (be2[k] - m2[k]*s2) * Wk3[k*256 + tid];
        }
        wsf[776 + tid] = u * LOG2E;
    }
}

// ---------------- main kernel ------------------------------------------------
__global__ __launch_bounds__(NTH, 2) void lstm_ae_mfma(
    const float* __restrict__ x,
    const float* __restrict__ b1,
    const unsigned short* __restrict__ WS,
    float* __restrict__ out)
{
    // A-fragment planes, fp16: [buf][kk][lane*8+j]; spread-row map:
    // batch row br -> A-row (br&1)+4*(br>>1); other A-rows stay exact zero.
    __shared__ __align__(16) _Float16 AZ1[2][5][512];   // raw h1 (kk 0-3) + x (kk 4)
    __shared__ __align__(16) _Float16 AH2[2][2][512];   // raw h2
    __shared__ __align__(16) _Float16 AH3[2][2][512];   // raw h3
    __shared__ __align__(16) _Float16 AH4[2][4][512];   // raw h4

    const int tid = threadIdx.x;
    const int w = tid >> 6, l = tid & 63;
    const int l15 = l & 15, q = l >> 4;
    const int h8 = (l15 >> 3) & 1;      // gate-exchange side for cell2/cell3
    const int b0 = blockIdx.x * BT;
    const int arow0 = 4*q;              // lane's A-rows 4q,4q+1 = batch 2q,2q+1

    // ---- per-lane constants ----
    const int u1 = 16*w + l15;                   // z1/z4 cell column (0..127)
    const int kk1 = u1 >> 5;
    const int sbase1 = ((u1>>3)&3)*128 + (u1&7);

    // gate-permuted unit mapping shared by cell2 and cell3: one cell/lane
    const int un = 8*w + (l15 & 7);              // unit 0..63
    const int s2w = (w&3)*128 + (arow0 + h8)*8 + (l15&7); // A-index, plane w>>2

    const float* wsf = (const float*)(WS + (size_t)FS_EXT*512);

    float z1b[4], z4b[4], z2b[2], z3b[2];
    #pragma unroll
    for (int i = 0; i < 4; ++i){
        z1b[i] = b1[(w + 8*i)*16 + l15] * LOG2E;
        z4b[i] = wsf[(w + 8*i)*16 + l15];        // folded b4' (log2 domain)
    }
    #pragma unroll
    for (int i = 0; i < 2; ++i){
        z2b[i] = wsf[520 + (2*i + h8)*64 + un];  // folded b2'
        z3b[i] = wsf[776 + (2*i + h8)*64 + un];  // folded b3'
    }
    const float bdv = ((w == 4 || w == 5) && l15 < 8) ? wsf[512 + l15] : 0.0f; // bd'

    // ---- encoder weights pinned in AGPRs (128 AGPR) ----
    half8 wz1[4][5], wz2[2][6];
    #pragma unroll
    for (int i = 0; i < 4; ++i)
        #pragma unroll
        for (int kk = 0; kk < 5; ++kk){
            wz1[i][kk] = *(const half8*)(WS + (size_t)(FS_Z1 + (w+8*i)*5 + kk)*512 + l*8);
            PINA(wz1[i][kk]);
        }
    #pragma unroll
    for (int i = 0; i < 2; ++i)
        #pragma unroll
        for (int kk = 0; kk < 6; ++kk){
            wz2[i][kk] = *(const half8*)(WS + (size_t)(FS_Z2 + (2*w+i)*6 + kk)*512 + l*8);
            PINA(wz2[i][kk]);
        }

    // ---- prologue: zero all planes, stage x(0) at spread rows ----
    for (int i = tid; i < 2560; i += NTH) ((int*)AZ1)[i] = 0;
    for (int i = tid; i < 2048; i += NTH) ((int*)AH4)[i] = 0;
    for (int i = tid; i < 1024; i += NTH){ ((int*)AH2)[i] = 0; ((int*)AH3)[i] = 0; }
    if (tid < 64){
        const int br = tid >> 3, ar = (br & 1) + 4*(br >> 1);
        AZ1[0][4][ar*8 + (tid&7)] = (_Float16)x[(size_t)(b0+br)*(TT*NF) + (tid&7)];
    }
    float c1r[2] = {0,0}, c4r[2] = {0,0};
    float c2r = 0.0f, c3r = 0.0f;
    __syncthreads();

    // ===================== encoder: ONE barrier per region ==================
    // region T (phase PE = T&1, LITERAL): z1(T+1)+cell1(T+1) | z2(T)+cell2(T)
#define ENC_REGION(T, PE) do { \
    half8 a5[5]; \
    _Pragma("unroll") \
    for (int kk = 0; kk < 5; ++kk) a5[kk] = *(const half8*)&AZ1[(PE)^1][kk][l*8]; \
    if ((T) + 1 < TT){ \
        float xnext = 0.0f; \
        if (tid < 64 && (T) + 2 < TT) \
            xnext = x[(size_t)(b0+(tid>>3))*(TT*NF) + (size_t)((T)+2)*NF + (tid&7)]; \
        floatx4 acc[4]; \
        _Pragma("unroll") \
        for (int i = 0; i < 4; ++i) acc[i] = (floatx4){z1b[i],z1b[i],z1b[i],z1b[i]}; \
        _Pragma("unroll") \
        for (int kk = 0; kk < 5; ++kk) \
            _Pragma("unroll") \
            for (int i = 0; i < 4; ++i) \
                acc[i] = MFMAH(a5[kk], wz1[i][kk], acc[i]); \
        _Pragma("unroll") \
        for (int r = 0; r < 2; ++r){ \
            float ig = sigmoid2_(acc[0][r]); \
            float fg = sigmoid2_(acc[1][r]); \
            float gg = selug2_(acc[2][r]); \
            float og = sigmoid2_(acc[3][r]); \
            float c = fg*c1r[r] + ig*gg; c1r[r] = c; \
            float h = og*selu_(c); \
            AZ1[(PE)][kk1][sbase1 + (arow0 + r)*8] = (_Float16)h; \
        } \
        if (tid < 64 && (T) + 2 < TT){ \
            const int br = tid >> 3, ar = (br & 1) + 4*(br >> 1); \
            AZ1[(PE)][4][ar*8 + (tid&7)] = (_Float16)xnext; \
        } \
    } \
    if ((T) >= 0){ \
        floatx4 a2[2]; \
        _Pragma("unroll") \
        for (int i = 0; i < 2; ++i) a2[i] = (floatx4){z2b[i],z2b[i],z2b[i],z2b[i]}; \
        _Pragma("unroll") \
        for (int kk = 0; kk < 4; ++kk) \
            _Pragma("unroll") \
            for (int i = 0; i < 2; ++i) \
                a2[i] = MFMAH(a5[kk], wz2[i][kk], a2[i]); \
        _Pragma("unroll") \
        for (int kk = 4; kk < 6; ++kk){ \
            half8 a = *(const half8*)&AH2[(PE)][kk-4][l*8]; \
            _Pragma("unroll") \
            for (int i = 0; i < 2; ++i) \
                a2[i] = MFMAH(a, wz2[i][kk], a2[i]); \
        } \
        float keep0 = h8 ? a2[0][1] : a2[0][0]; \
        float keep1 = h8 ? a2[1][1] : a2[1][0]; \
        float give0 = h8 ? a2[0][0] : a2[0][1]; \
        float give1 = h8 ? a2[1][0] : a2[1][1]; \
        float e0 = __shfl_xor(give0, 8); \
        float e1 = __shfl_xor(give1, 8); \
        float zi = h8 ? e0    : keep0; \
        float zf = h8 ? keep0 : e0; \
        float zg = h8 ? e1    : keep1; \
        float zo = h8 ? keep1 : e1; \
        float ig = sigmoid2_(zi); \
        float fg = sigmoid2_(zf); \
        float gg = selug2_(zg); \
        float og = sigmoid2_(zo); \
        float c = fg*c2r + ig*gg; c2r = c; \
        float h2 = og*selu_(c); \
        AH2[(PE)^1][w>>2][s2w] = (_Float16)h2; \
    } \
    __syncthreads(); \
} while(0)

    ENC_REGION(-1, 1);
    for (int t = 0; t < TT; t += 2){
        ENC_REGION(t, 0);
        ENC_REGION(t + 1, 1);
    }

    // ===================== bottleneck =====================
    // h2(TT-1) planes are in AH2[0] (raw; BN2 folded into Wk3).
    floatx4 xz3r[2];
    #pragma unroll
    for (int i = 0; i < 2; ++i) xz3r[i] = (floatx4){z3b[i],z3b[i],z3b[i],z3b[i]};
    #pragma unroll
    for (int kk = 0; kk < 2; ++kk){
        half8 a = *(const half8*)&AH2[0][kk][l*8];
        #pragma unroll
        for (int i = 0; i < 2; ++i){
            half8 b = *(const half8*)(WS + (size_t)(FS_X3 + (2*w+i)*2 + kk)*512 + l*8);
            xz3r[i] = MFMAH(a, b, xz3r[i]);
        }
    }

    // ---- decoder weights pinned in AGPRs (encoder AGPRs now dead) ----
    half8 wz4[4][6], wr3[2][2], wd4[4];
    #pragma unroll
    for (int i = 0; i < 4; ++i)
        #pragma unroll
        for (int kk = 0; kk < 6; ++kk){
            wz4[i][kk] = *(const half8*)(WS + (size_t)(FS_Z4 + (w+8*i)*6 + kk)*512 + l*8);
            PINA(wz4[i][kk]);
        }
    #pragma unroll
    for (int i = 0; i < 2; ++i)
        #pragma unroll
        for (int kk = 0; kk < 2; ++kk){
            wr3[i][kk] = *(const half8*)(WS + (size_t)(FS_Z3 + (2*w+i)*2 + kk)*512 + l*8);
            PINA(wr3[i][kk]);
        }
    if (w == 4 || w == 5){
        #pragma unroll
        for (int kk = 0; kk < 4; ++kk){
            wd4[kk] = *(const half8*)(WS + (size_t)(FS_DN + kk)*512 + l*8);
            PINA(wd4[kk]);
        }
    }
    __syncthreads();

    // ===================== decoder: ONE barrier per region ==================
    // region T (phase PE literal): z3(T+1)+cell3(T+1) | dense(T-1) on
    // w4 (PE=1) / w5 (PE=0) | z4(T)+cell4(T)
#define DEC_REGION(T, PE) do { \
    half8 a3k0 = *(const half8*)&AH3[(PE)^1][0][l*8]; \
    half8 a3k1 = *(const half8*)&AH3[(PE)^1][1][l*8]; \
    if ((T) + 1 < TT){ \
        floatx4 a3[2]; \
        a3[0] = xz3r[0]; a3[1] = xz3r[1]; \
        _Pragma("unroll") \
        for (int i = 0; i < 2; ++i){ \
            a3[i] = MFMAH(a3k0, wr3[i][0], a3[i]); \
            a3[i] = MFMAH(a3k1, wr3[i][1], a3[i]); \
        } \
        float keep0 = h8 ? a3[0][1] : a3[0][0]; \
        float keep1 = h8 ? a3[1][1] : a3[1][0]; \
        float give0 = h8 ? a3[0][0] : a3[0][1]; \
        float give1 = h8 ? a3[1][0] : a3[1][1]; \
        float e0 = __shfl_xor(give0, 8); \
        float e1 = __shfl_xor(give1, 8); \
        float zi = h8 ? e0    : keep0; \
        float zf = h8 ? keep0 : e0; \
        float zg = h8 ? e1    : keep1; \
        float zo = h8 ? keep1 : e1; \
        float ig = sigmoid2_(zi); \
        float fg = sigmoid2_(zf); \
        float gg = selug2_(zg); \
        float og = sigmoid2_(zo); \
        float c = fg*c3r + ig*gg; c3r = c; \
        float h = og*selu_(c); \
        AH3[(PE)][w>>2][s2w] = (_Float16)h; \
    } \
    { \
        const bool dw = (PE) ? (w == 4) : (w == 5); \
        if (dw && (T) > 0){ \
            floatx4 ad = (floatx4){bdv,bdv,bdv,bdv}; \
            _Pragma("unroll") \
            for (int kk = 0; kk < 4; ++kk){ \
                half8 a = *(const half8*)&AH4[(PE)][kk][l*8]; \
                ad = MFMAH(a, wd4[kk], ad); \
            } \
            if (l15 < 8){ \
                _Pragma("unroll") \
                for (int r = 0; r < 2; ++r) \
                    out[(size_t)(b0 + 2*q + r)*(TT*NF) + (size_t)((T)-1)*NF + l15] = ad[r]; \
            } \
        } \
    } \
    if ((T) >= 0){ \
        floatx4 a4[4]; \
        _Pragma("unroll") \
        for (int i = 0; i < 4; ++i) a4[i] = (floatx4){z4b[i],z4b[i],z4b[i],z4b[i]}; \
        _Pragma("unroll") \
        for (int i = 0; i < 4; ++i){ \
            a4[i] = MFMAH(a3k0, wz4[i][0], a4[i]); \
            a4[i] = MFMAH(a3k1, wz4[i][1], a4[i]); \
        } \
        _Pragma("unroll") \
        for (int kk = 2; kk < 6; ++kk){ \
            half8 a = *(const half8*)&AH4[(PE)][kk-2][l*8]; \
            _Pragma("unroll") \
            for (int i = 0; i < 4; ++i) \
                a4[i] = MFMAH(a, wz4[i][kk], a4[i]); \
        } \
        _Pragma("unroll") \
        for (int r = 0; r < 2; ++r){ \
            float ig = sigmoid2_(a4[0][r]); \
            float fg = sigmoid2_(a4[1][r]); \
            float gg = selug2_(a4[2][r]); \
            float og = sigmoid2_(a4[3][r]); \
            float c = fg*c4r[r] + ig*gg; c4r[r] = c; \
            float h = og*selu_(c); \
            AH4[(PE)^1][kk1][sbase1 + (arow0 + r)*8] = (_Float16)h; \
        } \
    } \
    __syncthreads(); \
} while(0)

    DEC_REGION(-1, 1);
    for (int t = 0; t < TT; t += 2){
        DEC_REGION(t, 0);
        DEC_REGION(t + 1, 1);
    }

    // epilogue: dense(TT-1) on w5; h4(TT-1) was written into AH4[0] by t=127
    if (w == 5){
        floatx4 ad = (floatx4){bdv,bdv,bdv,bdv};
        #pragma unroll
        for (int kk = 0; kk < 4; ++kk){
            half8 a = *(const half8*)&AH4[0][kk][l*8];
            ad = MFMAH(a, wd4[kk], ad);
        }
        if (l15 < 8){
            #pragma unroll
            for (int r = 0; r < 2; ++r)
                out[(size_t)(b0 + 2*q + r)*(TT*NF) + (size_t)(TT-1)*NF + l15] = ad[r];
        }
    }
}

extern "C" void kernel_launch(void* const* d_in, const int* in_sizes, int n_in,
                              void* d_out, int out_size, void* d_ws, size_t ws_size,
                              hipStream_t stream) {
    const float* x   = (const float*)d_in[0];
    const float* Wk1 = (const float*)d_in[1];  const float* Wr1 = (const float*)d_in[2];
    const float* b1  = (const float*)d_in[3];
    const float* g1  = (const float*)d_in[4];  const float* be1 = (const float*)d_in[5];
    const float* m1  = (const float*)d_in[6];  const float* v1  = (const float*)d_in[7];
    const float* Wk2 = (const float*)d_in[8];  const float* Wr2 = (const float*)d_in[9];
    const float* b2  = (const float*)d_in[10];
    const float* g2  = (const float*)d_in[11]; const float* be2 = (const float*)d_in[12];
    const float* m2  = (const float*)d_in[13]; const float* v2  = (const float*)d_in[14];
    const float* Wk3 = (const float*)d_in[15]; const float* Wr3 = (const float*)d_in[16];
    const float* b3  = (const float*)d_in[17];
    const float* g3  = (const float*)d_in[18]; const float* be3 = (const float*)d_in[19];
    const float* m3  = (const float*)d_in[20]; const float* v3  = (const float*)d_in[21];
    const float* Wk4 = (const float*)d_in[22]; const float* Wr4 = (const float*)d_in[23];
    const float* b4  = (const float*)d_in[24];
    const float* g4  = (const float*)d_in[25]; const float* be4 = (const float*)d_in[26];
    const float* m4  = (const float*)d_in[27]; const float* v4  = (const float*)d_in[28];
    const float* Wd  = (const float*)d_in[29]; const float* bd  = (const float*)d_in[30];

    unsigned short* ws = (unsigned short*)d_ws;

    pack_kernel<<<dim3(N_FRAGS), dim3(64), 0, stream>>>(Wk1, Wr1, Wk2, Wr2, Wk3, Wr3,
                                                        Wk4, Wr4, Wd,
                                                        g1, v1, g2, v2, g3, v3, g4, v4, ws);
    foldbias_kernel<<<dim3(1), dim3(512), 0, stream>>>(b2, b3, b4, bd,
                                                       g1, be1, m1, v1, g2, be2, m2, v2,
                                                       g3, be3, m3, v3, g4, be4, m4, v4,
                                                       Wk2, Wk3, Wk4, Wd, ws);
    lstm_ae_mfma<<<dim3(NBLK), dim3(NTH), 0, stream>>>(
        x, b1, (const unsigned short*)ws, (float*)d_out);
}